// Round 7
// baseline (206.242 us; speedup 1.0000x reference)
//
#include <hip/hip_runtime.h>
#include <math.h>

// GraspCVAE loss, MI355X — round 7.
// Round-6 failure: hipLaunchCooperativeKernel failed silently (unchecked rc).
// Round-5 diagnosis: (a) 1.5M contended atomicMin combine, (b) finalize reads
// written as dependent fminf(aread) chains (24-96 serial ~700cyc RMW RTTs per
// point) -> 90us tail. This round: ONE ordinary 768-block worker kernel using
// round-4's plain disjoint-slice stores + round-5's proven fence/counter
// protocol + ILP-batched atomic reads in finalize. Counters zeroed by a tiny
// hipMemsetAsync (capturable memset node). 2 stream ops total.
//   blocks [0,384):  obj->hand NN (j-split 4, packed-index keys, plain stores)
//                    last split block per (b,tile) finalizes 1024 obj points
//   blocks [384,768): hand->obj NN (12 obj chunks, plain stores)
//                    last chunk block per b finalizes loss_h/recon/KLD
//   last of 128 finalizers combines into out[0].
// Fallback: tiny-ws PATH C.

#define NB 32
#define NH 778
#define NO 3000
#define NZ 64
#define NP 204

#define P_OBJ 4
#define OBJ_PTS 1024
#define OBJ_TILES 3                   // ceil(3000/1024)
#define JSPLIT 4
#define JCH 195                       // ceil(778/4)
#define HC 12                         // hand-side obj chunks
#define HCS 250                       // 3000/12
#define OBJ_BLKS (NB * OBJ_TILES * JSPLIT)    // 384
#define HAND_BLKS (NB * HC)                   // 384
#define TOT_BLKS (OBJ_BLKS + HAND_BLKS)       // 768
#define NKEY (NB * NO)                // 96000
#define NHT  (NB * NH)                // 24896
#define N_FINAL (NB * OBJ_TILES + NB) // 128 finalize contributors

typedef unsigned int uint32;

__device__ __constant__ int c_prior[NP] = {
  697,698,699,700,712,713,714,715,737,738,739,740,741,743,744,745,746,748,749,750,
  753,754,755,756,757,758,759,760,761,762,763,764,765,766,767,768,
  46,47,48,49,164,165,166,167,194,195,223,237,238,280,281,298,301,317,320,323,
  324,325,326,327,328,329,330,331,332,333,340,341,342,343,344,345,346,347,348,349,
  350,351,352,353,354,355,
  356,357,358,359,375,376,386,387,396,397,402,403,413,429,433,434,435,436,437,438,
  439,440,441,442,443,444,452,453,454,455,456,459,460,461,462,463,464,465,466,467,
  468,469,470,471,484,485,486,496,497,506,507,513,514,524,545,546,547,548,549,550,
  551,552,553,555,563,564,565,566,567,570,572,573,574,575,576,577,578,
  580,581,582,583,600,601,602,614,615,624,625,630,631,641,663,664,665,666,667,668,
  670,672,680,681,682,683,684,686,687,688,689,690,691,692,693,694,695,
  73,96,98,99,772,774,775,777
};

__device__ inline float wave_sum(float v) {
  v += __shfl_down(v, 32);
  v += __shfl_down(v, 16);
  v += __shfl_down(v, 8);
  v += __shfl_down(v, 4);
  v += __shfl_down(v, 2);
  v += __shfl_down(v, 1);
  return v;
}

// pack candidate index into low 10 mantissa bits; float order ~ (t, j)
__device__ inline float packkey(float t, int j) {
  return __uint_as_float((__float_as_uint(t) & 0xFFFFFC00u) | (uint32)j);
}
// coherent device-scope read (RMW; proven pattern from round 5)
__device__ inline float aread(const float* p) {
  return atomicAdd((float*)p, 0.0f);
}

__device__ inline void final_combine(float* accs, float* out) {
  float a[8];
  #pragma unroll
  for (int q = 0; q < 8; ++q) a[q] = aread(&accs[q]);
  const float recon_loss = a[6] / (float)NB;
  const float kld = -0.5f * a[7] / (float)NB * 10.f;
  const float penetr = 100.f * a[0] / (float)NB;
  const float npts = a[1];
  const float contact = (npts > 0.f) ? (3000.f * a[2] / ((float)NB * npts)) : 0.f;
  const float consistency = -5.f * a[3] / (npts + 0.0001f);
  const float lossh = 35.f * (1.f - 0.005f) * (a[5] / (float)(NB * NH));
  const float losso = 30.f * (1.f - 0.005f) * (a[4] / (float)(NB * NO));
  out[0] = recon_loss + 0.1f * kld + 1000.f * penetr + 10.f * contact
         + 10.f * consistency + lossh + losso;
}

// accs: 0 penetr, 1 npts, 2 contact, 3 consist, 4 loss_o, 5 loss_h, 6 recon_sq, 7 kld
__global__ __launch_bounds__(256) void worker(
    const float* __restrict__ recon, const float* __restrict__ gt,
    const float* __restrict__ rnorm, const float* __restrict__ gnorm,
    const float* __restrict__ obj,
    const float* __restrict__ mean, const float* __restrict__ logv,
    const float* __restrict__ vw,
    float* __restrict__ keyR, float* __restrict__ keyG,
    float* __restrict__ minHR, float* __restrict__ minHG,
    float* __restrict__ accs, int* __restrict__ gcnt,
    int* __restrict__ cntObj, int* __restrict__ cntHand,
    float* __restrict__ out)
{
  __shared__ float4 shA[HCS];    // 250: recon-split / obj-chunk staging
  __shared__ float4 shB[NP];     // 204: gt-split staging, reused for prior
  __shared__ float red[4][5];
  __shared__ int flag;
  const int bid = blockIdx.x;
  const int tid = threadIdx.x;
  const int lane = tid & 63, wv = tid >> 6;

  if (bid < OBJ_BLKS) {
    // ================= obj -> hand NN (j-split 4) =================
    const int b     = bid / (OBJ_TILES * JSPLIT);
    const int rem   = bid % (OBJ_TILES * JSPLIT);
    const int tile  = rem / JSPLIT;
    const int split = rem % JSPLIT;
    const int jbase = split * JCH;
    const int jcnt  = (NH - jbase < JCH) ? (NH - jbase) : JCH;

    for (int i = tid; i < jcnt; i += 256) {
      const float* p = recon + ((size_t)b * NH + jbase + i) * 3;
      float x = p[0], y = p[1], z = p[2];
      shA[i] = make_float4(x, y, z, x*x + y*y + z*z);
      const float* q = gt + ((size_t)b * NH + jbase + i) * 3;
      float gx = q[0], gy = q[1], gz = q[2];
      shB[i] = make_float4(gx, gy, gz, gx*gx + gy*gy + gz*gz);
    }
    __syncthreads();

    float nx[P_OBJ], ny[P_OBJ], nz[P_OBJ];
    int ob[P_OBJ]; bool val[P_OBJ];
    #pragma unroll
    for (int m = 0; m < P_OBJ; ++m) {
      int o = tile * OBJ_PTS + m * 256 + tid;
      ob[m] = o; val[m] = (o < NO);
      float x = 0.f, y = 0.f, z = 0.f;
      if (val[m]) {
        const float* op = obj + ((size_t)b * NO + o) * 3;
        x = op[0]; y = op[1]; z = op[2];
      }
      nx[m] = -2.f * x; ny[m] = -2.f * y; nz[m] = -2.f * z;
    }

    float bR[P_OBJ], bG[P_OBJ];
    #pragma unroll
    for (int m = 0; m < P_OBJ; ++m) { bR[m] = 3.4e38f; bG[m] = 3.4e38f; }

    int i = 0;
    for (; i + 1 < jcnt; i += 2) {
      float4 h0 = shA[i], h1 = shA[i + 1];
      #pragma unroll
      for (int m = 0; m < P_OBJ; ++m) {
        float t0 = fmaf(nx[m], h0.x, h0.w); t0 = fmaf(ny[m], h0.y, t0); t0 = fmaf(nz[m], h0.z, t0);
        float t1 = fmaf(nx[m], h1.x, h1.w); t1 = fmaf(ny[m], h1.y, t1); t1 = fmaf(nz[m], h1.z, t1);
        bR[m] = fminf(bR[m], fminf(packkey(t0, jbase + i), packkey(t1, jbase + i + 1)));
      }
      float4 g0 = shB[i], g1 = shB[i + 1];
      #pragma unroll
      for (int m = 0; m < P_OBJ; ++m) {
        float t0 = fmaf(nx[m], g0.x, g0.w); t0 = fmaf(ny[m], g0.y, t0); t0 = fmaf(nz[m], g0.z, t0);
        float t1 = fmaf(nx[m], g1.x, g1.w); t1 = fmaf(ny[m], g1.y, t1); t1 = fmaf(nz[m], g1.z, t1);
        bG[m] = fminf(bG[m], fminf(packkey(t0, jbase + i), packkey(t1, jbase + i + 1)));
      }
    }
    if (i < jcnt) {
      float4 h0 = shA[i];
      float4 g0 = shB[i];
      #pragma unroll
      for (int m = 0; m < P_OBJ; ++m) {
        float t0 = fmaf(nx[m], h0.x, h0.w); t0 = fmaf(ny[m], h0.y, t0); t0 = fmaf(nz[m], h0.z, t0);
        bR[m] = fminf(bR[m], packkey(t0, jbase + i));
        float u0 = fmaf(nx[m], g0.x, g0.w); u0 = fmaf(ny[m], g0.y, u0); u0 = fmaf(nz[m], g0.z, u0);
        bG[m] = fminf(bG[m], packkey(u0, jbase + i));
      }
    }

    #pragma unroll
    for (int m = 0; m < P_OBJ; ++m) {
      if (!val[m]) continue;
      const size_t idx = (size_t)split * NKEY + (size_t)b * NO + ob[m];
      keyR[idx] = bR[m];
      keyG[idx] = bG[m];
    }

    // release stores, bump group counter
    __threadfence();
    __syncthreads();
    if (tid == 0)
      flag = (atomicAdd(&cntObj[b * OBJ_TILES + tile], 1) == JSPLIT - 1) ? 1 : 0;
    __syncthreads();
    if (!flag) return;

    // ====== finalize (b,tile): last split block; ILP-batched reads ======
    if (tid < NP) {
      int j = c_prior[tid];
      const float* p = recon + ((size_t)b * NH + j) * 3;
      float x = p[0], y = p[1], z = p[2];
      shB[tid] = make_float4(x, y, z, x*x + y*y + z*z);
    }
    __syncthreads();

    float penetr = 0.f, nptsv = 0.f, contactv = 0.f, consistv = 0.f, lossov = 0.f;
    #pragma unroll
    for (int m = 0; m < P_OBJ; ++m) {
      if (!val[m]) continue;
      const float ox = -0.5f * nx[m], oy = -0.5f * ny[m], oz = -0.5f * nz[m];
      const float o2 = ox*ox + oy*oy + oz*oz;
      const size_t base = (size_t)b * NO + ob[m];

      // 8 independent coherent reads, then tree-reduce (no serial RTT chain)
      float r0 = aread(&keyR[0 * NKEY + base]);
      float r1 = aread(&keyR[1 * NKEY + base]);
      float r2 = aread(&keyR[2 * NKEY + base]);
      float r3 = aread(&keyR[3 * NKEY + base]);
      float q0 = aread(&keyG[0 * NKEY + base]);
      float q1 = aread(&keyG[1 * NKEY + base]);
      float q2 = aread(&keyG[2 * NKEY + base]);
      float q3 = aread(&keyG[3 * NKEY + base]);
      float kR = fminf(fminf(r0, r1), fminf(r2, r3));
      float kG = fminf(fminf(q0, q1), fminf(q2, q3));

      uint32 kRb = __float_as_uint(kR), kGb = __float_as_uint(kG);
      int idxR = (int)(kRb & 0x3FFu), idxG = (int)(kGb & 0x3FFu);
      float d2R = fmaxf(__uint_as_float(kRb & 0xFFFFFC00u) + o2, 0.f);
      float d2G = fmaxf(__uint_as_float(kGb & 0xFFFFFC00u) + o2, 0.f);

      float bP = 3.4e38f;
      for (int k = 0; k < NP; k += 2) {
        float4 h0 = shB[k], h1 = shB[k + 1];
        float t0 = fmaf(nx[m], h0.x, h0.w); t0 = fmaf(ny[m], h0.y, t0); t0 = fmaf(nz[m], h0.z, t0);
        float t1 = fmaf(nx[m], h1.x, h1.w); t1 = fmaf(ny[m], h1.y, t1); t1 = fmaf(nz[m], h1.z, t1);
        bP = fminf(bP, fminf(t0, t1));
      }
      float d2P = fmaxf(bP + o2, 0.f);

      const float* hR = recon + ((size_t)b * NH + idxR) * 3;
      const float* nR = rnorm + ((size_t)b * NH + idxR) * 3;
      float dotR = (ox - hR[0]) * nR[0] + (oy - hR[1]) * nR[1] + (oz - hR[2]) * nR[2];
      const float* hG = gt + ((size_t)b * NH + idxG) * 3;
      const float* nG = gnorm + ((size_t)b * NH + idxG) * 3;
      float dotG = (ox - hG[0]) * nG[0] + (oy - hG[1]) * nG[1] + (oz - hG[2]) * nG[2];

      float sgnR = (dotR > 0.f) ? 1.f : ((dotR < 0.f) ? -1.f : 0.f);
      float sgnG = (dotG > 0.f) ? 1.f : ((dotG < 0.f) ? -1.f : 0.f);
      float sR_ = sqrtf(d2R), sG_ = sqrtf(d2G);
      float o2h = sR_ * sgnR, o2hg = sG_ * sgnG;

      bool interior = dotR < 0.f;
      bool cmap = sG_ < 0.005f;
      bool rcmap = sR_ < 0.005f;

      penetr   += interior ? d2R : 0.f;
      nptsv    += cmap ? 1.f : 0.f;
      contactv += cmap ? d2P : 0.f;
      consistv += (cmap && rcmap) ? 1.f : 0.f;
      float w = (o2h < 0.f) ? 1.5f
              : (((o2hg < 0.01f) && (o2hg > -0.005f)) ? 1.f : 0.1f);
      lossov += fabsf(o2h - o2hg) * w;
    }

    float vals[5] = {penetr, nptsv, contactv, consistv, lossov};
    #pragma unroll
    for (int q = 0; q < 5; ++q) {
      float s = wave_sum(vals[q]);
      if (lane == 0) red[wv][q] = s;
    }
    __syncthreads();
    if (tid < 5) {
      float s = red[0][tid] + red[1][tid] + red[2][tid] + red[3][tid];
      atomicAdd(&accs[tid], s);
    }
    __syncthreads();
    if (tid == 0) {
      __threadfence();
      if (atomicAdd(gcnt, 1) == N_FINAL - 1) final_combine(accs, out);
    }
  } else {
    // ================= hand -> obj NN (12 chunks) =================
    const int bid2 = bid - OBJ_BLKS;
    const int oc = bid2 % HC;
    const int b  = bid2 / HC;

    const float* Ob = obj + ((size_t)b * NO + oc * HCS) * 3;
    for (int i2 = tid; i2 < HCS; i2 += 256) {
      float x = Ob[3*i2], y = Ob[3*i2+1], z = Ob[3*i2+2];
      shA[i2] = make_float4(x, y, z, x*x + y*y + z*z);
    }
    __syncthreads();

    float nrx[4], nry[4], nrz[4];
    float ngx[4], ngy[4], ngz[4];
    bool val[4];
    #pragma unroll
    for (int m = 0; m < 4; ++m) {
      int j = m * 256 + tid;
      val[m] = (j < NH);
      float rx = 0.f, ry = 0.f, rz = 0.f, gx = 0.f, gy = 0.f, gz = 0.f;
      if (val[m]) {
        const float* rp = recon + ((size_t)b * NH + j) * 3;
        const float* gp = gt    + ((size_t)b * NH + j) * 3;
        rx = rp[0]; ry = rp[1]; rz = rp[2];
        gx = gp[0]; gy = gp[1]; gz = gp[2];
      }
      nrx[m] = -2.f*rx; nry[m] = -2.f*ry; nrz[m] = -2.f*rz;
      ngx[m] = -2.f*gx; ngy[m] = -2.f*gy; ngz[m] = -2.f*gz;
    }

    float mR[4], mG[4];
    #pragma unroll
    for (int m = 0; m < 4; ++m) { mR[m] = 3.4e38f; mG[m] = 3.4e38f; }

    for (int k = 0; k < HCS; k += 2) {
      float4 o0 = shA[k], o1 = shA[k + 1];
      #pragma unroll
      for (int m = 0; m < 4; ++m) {
        float t0 = fmaf(nrx[m], o0.x, o0.w); t0 = fmaf(nry[m], o0.y, t0); t0 = fmaf(nrz[m], o0.z, t0);
        float t1 = fmaf(nrx[m], o1.x, o1.w); t1 = fmaf(nry[m], o1.y, t1); t1 = fmaf(nrz[m], o1.z, t1);
        mR[m] = fminf(mR[m], fminf(t0, t1));
        float u0 = fmaf(ngx[m], o0.x, o0.w); u0 = fmaf(ngy[m], o0.y, u0); u0 = fmaf(ngz[m], o0.z, u0);
        float u1 = fmaf(ngx[m], o1.x, o1.w); u1 = fmaf(ngy[m], o1.y, u1); u1 = fmaf(ngz[m], o1.z, u1);
        mG[m] = fminf(mG[m], fminf(u0, u1));
      }
    }

    #pragma unroll
    for (int m = 0; m < 4; ++m) {
      if (!val[m]) continue;
      int j = m * 256 + tid;
      const size_t idx = (size_t)oc * NHT + (size_t)b * NH + j;
      minHR[idx] = mR[m];
      minHG[idx] = mG[m];
    }

    __threadfence();
    __syncthreads();
    if (tid == 0)
      flag = (atomicAdd(&cntHand[b], 1) == HC - 1) ? 1 : 0;
    __syncthreads();
    if (!flag) return;

    // ====== finalize batch b: loss_h + recon_loss + KLD ======
    float lossh = 0.f, rsum = 0.f, ksum = 0.f;
    #pragma unroll
    for (int m = 0; m < 4; ++m) {
      int j = m * 256 + tid;
      if (j >= NH) continue;
      const size_t base = (size_t)b * NH + j;

      // 24 independent coherent reads, then tree-reduce
      float tR[HC], tG[HC];
      #pragma unroll
      for (int c = 0; c < HC; ++c) {
        tR[c] = aread(&minHR[(size_t)c * NHT + base]);
        tG[c] = aread(&minHG[(size_t)c * NHT + base]);
      }
      float mRt = tR[0], mGt = tG[0];
      #pragma unroll
      for (int c = 1; c < HC; ++c) {
        mRt = fminf(mRt, tR[c]);
        mGt = fminf(mGt, tG[c]);
      }

      const float* rp = recon + base * 3;
      const float* gp = gt    + base * 3;
      float rx = rp[0], ry = rp[1], rz = rp[2];
      float gx = gp[0], gy = gp[1], gz = gp[2];
      float d0 = rx - gx, d1 = ry - gy, d2 = rz - gz;
      rsum += d0*d0 + d1*d1 + d2*d2;

      float r2 = rx*rx + ry*ry + rz*rz;
      float g2 = gx*gx + gy*gy + gz*gz;
      float d2Rh = fmaxf(mRt + r2, 0.f);
      float d2Gh = fmaxf(mGt + g2, 0.f);
      lossh += fabsf(sqrtf(d2Rh) - sqrtf(d2Gh)) * powf(vw[j], 0.4f);
    }
    if (tid < NZ) {
      float mm = mean[b * NZ + tid], lv = logv[b * NZ + tid];
      ksum = 1.f + lv - mm * mm - expf(lv);
    }

    float vals[3] = {lossh, rsum, ksum};
    #pragma unroll
    for (int q = 0; q < 3; ++q) {
      float s = wave_sum(vals[q]);
      if (lane == 0) red[wv][q] = s;
    }
    __syncthreads();
    if (tid < 3) {
      float s = red[0][tid] + red[1][tid] + red[2][tid] + red[3][tid];
      atomicAdd(&accs[5 + tid], s);
    }
    __syncthreads();
    if (tid == 0) {
      __threadfence();
      if (atomicAdd(gcnt, 1) == N_FINAL - 1) final_combine(accs, out);
    }
  }
}

// =========================== PATH C (tiny ws fallback) ===========================
__global__ __launch_bounds__(256) void obj_mono(
    const float* __restrict__ recon, const float* __restrict__ gt,
    const float* __restrict__ rnorm, const float* __restrict__ gnorm,
    const float* __restrict__ obj, float* __restrict__ accs)
{
  __shared__ float4 sR[NH];
  __shared__ float4 sG[NH];
  __shared__ float red[4][5];
  const int b = blockIdx.x / 12;
  const int tile = blockIdx.x % 12;
  const int tid = threadIdx.x;
  for (int i = tid; i < NH; i += 256) {
    const float* p = recon + ((size_t)b * NH + i) * 3;
    float x = p[0], y = p[1], z = p[2];
    sR[i] = make_float4(x, y, z, x*x + y*y + z*z);
    const float* q = gt + ((size_t)b * NH + i) * 3;
    float gx = q[0], gy = q[1], gz = q[2];
    sG[i] = make_float4(gx, gy, gz, gx*gx + gy*gy + gz*gz);
  }
  __syncthreads();
  const int o = tile * 256 + tid;
  float penetr = 0.f, nptsv = 0.f, contactv = 0.f, consistv = 0.f, lossov = 0.f;
  if (o < NO) {
    const float* op = obj + ((size_t)b * NO + o) * 3;
    const float ox = op[0], oy = op[1], oz = op[2];
    const float nx = -2.f*ox, ny = -2.f*oy, nz = -2.f*oz;
    const float o2 = ox*ox + oy*oy + oz*oz;
    float bR = 3.4e38f, bG = 3.4e38f; int iR = 0, iG = 0;
    for (int i = 0; i < NH; ++i) {
      float4 h = sR[i];
      float t = fmaf(nx, h.x, h.w); t = fmaf(ny, h.y, t); t = fmaf(nz, h.z, t);
      if (t < bR) { bR = t; iR = i; }
      float4 g = sG[i];
      float u = fmaf(nx, g.x, g.w); u = fmaf(ny, g.y, u); u = fmaf(nz, g.z, u);
      if (u < bG) { bG = u; iG = i; }
    }
    float bP = 3.4e38f;
    for (int k = 0; k < NP; ++k) {
      float4 h = sR[c_prior[k]];
      float t = fmaf(nx, h.x, h.w); t = fmaf(ny, h.y, t); t = fmaf(nz, h.z, t);
      bP = fminf(bP, t);
    }
    float d2R = fmaxf(bR + o2, 0.f);
    float d2G = fmaxf(bG + o2, 0.f);
    float d2P = fmaxf(bP + o2, 0.f);
    float4 hR = sR[iR];
    const float* nR = rnorm + ((size_t)b * NH + iR) * 3;
    float dotR = (ox-hR.x)*nR[0] + (oy-hR.y)*nR[1] + (oz-hR.z)*nR[2];
    float4 hG = sG[iG];
    const float* nG = gnorm + ((size_t)b * NH + iG) * 3;
    float dotG = (ox-hG.x)*nG[0] + (oy-hG.y)*nG[1] + (oz-hG.z)*nG[2];
    float sgnR = (dotR > 0.f) ? 1.f : ((dotR < 0.f) ? -1.f : 0.f);
    float sgnG = (dotG > 0.f) ? 1.f : ((dotG < 0.f) ? -1.f : 0.f);
    float sR_ = sqrtf(d2R), sG_ = sqrtf(d2G);
    float o2h = sR_*sgnR, o2hg = sG_*sgnG;
    bool interior = dotR < 0.f;
    bool cmap = sG_ < 0.005f, rcmap = sR_ < 0.005f;
    penetr = interior ? d2R : 0.f;
    nptsv = cmap ? 1.f : 0.f;
    contactv = cmap ? d2P : 0.f;
    consistv = (cmap && rcmap) ? 1.f : 0.f;
    float w = (o2h < 0.f) ? 1.5f : (((o2hg < 0.01f) && (o2hg > -0.005f)) ? 1.f : 0.1f);
    lossov = fabsf(o2h - o2hg) * w;
  }
  float vals[5] = {penetr, nptsv, contactv, consistv, lossov};
  const int lane = tid & 63, wv = tid >> 6;
  for (int q = 0; q < 5; ++q) {
    float s = wave_sum(vals[q]);
    if (lane == 0) red[wv][q] = s;
  }
  __syncthreads();
  if (tid < 5) {
    float s = red[0][tid] + red[1][tid] + red[2][tid] + red[3][tid];
    atomicAdd(&accs[tid], s);
  }
}

__global__ __launch_bounds__(256) void hand_full(
    const float* __restrict__ recon, const float* __restrict__ gt,
    const float* __restrict__ obj, const float* __restrict__ vw,
    float* __restrict__ accs)
{
  __shared__ float4 sO[500];
  __shared__ float red[4];
  const int b = blockIdx.x >> 2;
  const int j = ((blockIdx.x & 3) << 8) + threadIdx.x;
  const bool valid = j < NH;
  float rx=0,ry=0,rz=0,gx=0,gy=0,gz=0;
  if (valid) {
    const float* rp = recon + ((size_t)b * NH + j) * 3;
    const float* gp = gt + ((size_t)b * NH + j) * 3;
    rx=rp[0];ry=rp[1];rz=rp[2]; gx=gp[0];gy=gp[1];gz=gp[2];
  }
  const float nrx=-2.f*rx, nry=-2.f*ry, nrz=-2.f*rz;
  const float ngx=-2.f*gx, ngy=-2.f*gy, ngz=-2.f*gz;
  const float r2 = rx*rx+ry*ry+rz*rz, g2 = gx*gx+gy*gy+gz*gz;
  float mR = 3.4e38f, mG = 3.4e38f;
  for (int oc = 0; oc < 6; ++oc) {
    __syncthreads();
    const float* Ob = obj + ((size_t)b * NO + oc * 500) * 3;
    for (int i = threadIdx.x; i < 500; i += 256) {
      float x = Ob[3*i], y = Ob[3*i+1], z = Ob[3*i+2];
      sO[i] = make_float4(x, y, z, x*x + y*y + z*z);
    }
    __syncthreads();
    if (valid) {
      for (int k = 0; k < 500; ++k) {
        float4 o4 = sO[k];
        float t = fmaf(nrx,o4.x,o4.w); t = fmaf(nry,o4.y,t); t = fmaf(nrz,o4.z,t);
        mR = fminf(mR, t);
        float u = fmaf(ngx,o4.x,o4.w); u = fmaf(ngy,o4.y,u); u = fmaf(ngz,o4.z,u);
        mG = fminf(mG, u);
      }
    }
  }
  float lossh = valid ? fabsf(sqrtf(fmaxf(mR+r2,0.f)) - sqrtf(fmaxf(mG+g2,0.f))) * powf(vw[j], 0.4f) : 0.f;
  const int lane = threadIdx.x & 63, wv = threadIdx.x >> 6;
  float s = wave_sum(lossh);
  if (lane == 0) red[wv] = s;
  __syncthreads();
  if (threadIdx.x == 0) atomicAdd(&accs[5], red[0]+red[1]+red[2]+red[3]);
}

__global__ __launch_bounds__(256) void tail_nomins(
    const float* __restrict__ recon, const float* __restrict__ gt,
    const float* __restrict__ mean, const float* __restrict__ logv,
    float* __restrict__ accs)
{
  __shared__ float red[4][2];
  const int t = blockIdx.x * 256 + threadIdx.x;
  float rsum = 0.f, ksum = 0.f;
  if (t < NB * NH) {
    const float* rp = recon + (size_t)t * 3;
    const float* gp = gt + (size_t)t * 3;
    float d0 = rp[0]-gp[0], d1 = rp[1]-gp[1], d2 = rp[2]-gp[2];
    rsum = d0*d0 + d1*d1 + d2*d2;
  }
  if (t < NB * NZ) {
    float m = mean[t], lv = logv[t];
    ksum = 1.f + lv - m*m - expf(lv);
  }
  float vals[2] = {rsum, ksum};
  const int lane = threadIdx.x & 63, wv = threadIdx.x >> 6;
  for (int q = 0; q < 2; ++q) {
    float s = wave_sum(vals[q]);
    if (lane == 0) red[wv][q] = s;
  }
  __syncthreads();
  if (threadIdx.x < 2) {
    float s = red[0][threadIdx.x] + red[1][threadIdx.x] + red[2][threadIdx.x] + red[3][threadIdx.x];
    atomicAdd(&accs[6 + threadIdx.x], s);
  }
}

__global__ void init_small(float* accs) {
  int t = threadIdx.x;
  if (t < 8) accs[t] = 0.0f;
}

__global__ void final_fb(const float* __restrict__ a, float* __restrict__ out) {
  const float recon_loss = a[6] / (float)NB;
  const float kld = -0.5f * a[7] / (float)NB * 10.f;
  const float penetr = 100.f * a[0] / (float)NB;
  const float npts = a[1];
  const float contact = (npts > 0.f) ? (3000.f * a[2] / ((float)NB * npts)) : 0.f;
  const float consistency = -5.f * a[3] / (npts + 0.0001f);
  const float lossh = 35.f * (1.f - 0.005f) * (a[5] / (float)(NB * NH));
  const float losso = 30.f * (1.f - 0.005f) * (a[4] / (float)(NB * NO));
  out[0] = recon_loss + 0.1f*kld + 1000.f*penetr + 10.f*contact + 10.f*consistency + lossh + losso;
}

extern "C" void kernel_launch(void* const* d_in, const int* in_sizes, int n_in,
                              void* d_out, int out_size, void* d_ws, size_t ws_size,
                              hipStream_t stream) {
  const float* recon = (const float*)d_in[0];
  const float* gt    = (const float*)d_in[1];
  const float* rnorm = (const float*)d_in[2];
  const float* gnorm = (const float*)d_in[3];
  const float* obj   = (const float*)d_in[4];
  const float* mean  = (const float*)d_in[5];
  const float* logv  = (const float*)d_in[6];
  const float* vw    = (const float*)d_in[7];
  float* out = (float*)d_out;

  // ws layout: [0,64)   accs[16] floats
  //            [64,68)  gcnt
  //            [68,452) cntObj[96]
  //            [452,580) cntHand[32]
  //            [1024, ...) keyR[4*96000] keyG[4*96000] minHR[12*24896] minHG[12*24896]
  float* accs   = (float*)d_ws;
  int* gcnt     = (int*)((char*)d_ws + 64);
  int* cntObj   = (int*)((char*)d_ws + 68);
  int* cntHand  = (int*)((char*)d_ws + 452);
  float* keyR   = (float*)((char*)d_ws + 1024);
  float* keyG   = keyR + (size_t)JSPLIT * NKEY;
  float* minHR  = keyG + (size_t)JSPLIT * NKEY;
  float* minHG  = minHR + (size_t)HC * NHT;
  const size_t neededA = 1024 + (2ull * JSPLIT * NKEY + 2ull * HC * NHT) * sizeof(float);

  if (ws_size >= neededA) {
    // zero accs + all counters (capturable memset node, ~1us)
    hipMemsetAsync(d_ws, 0, 1024, stream);
    worker<<<TOT_BLKS, 256, 0, stream>>>(
        recon, gt, rnorm, gnorm, obj, mean, logv, vw,
        keyR, keyG, minHR, minHG, accs, gcnt, cntObj, cntHand, out);
  } else {
    init_small<<<1, 64, 0, stream>>>(accs);
    obj_mono<<<NB * 12, 256, 0, stream>>>(recon, gt, rnorm, gnorm, obj, accs);
    hand_full<<<NB * 4, 256, 0, stream>>>(recon, gt, obj, vw, accs);
    tail_nomins<<<(NB * NH + 255) / 256, 256, 0, stream>>>(recon, gt, mean, logv, accs);
    final_fb<<<1, 1, 0, stream>>>(accs, out);
  }
}

// Round 8
// 121.262 us; speedup vs baseline: 1.7008x; 1.7008x over previous
//
#include <hip/hip_runtime.h>
#include <math.h>

// GraspCVAE loss, MI355X — round 8.
// Verdict from R5/R7: in-kernel device-scope coherence (fences + atomic-RMW
// reads across 768 blocks) costs ~60-100us on gfx950; the kernel boundary is
// cheaper. So: back to the proven round-4 two-dispatch plain-store dataflow,
// with one structural improvement:
//   * prior-NN folded into mega1's obj-split blocks (candidates already in
//     LDS; sorted prior list with compile-time per-split offsets) -> 3rd
//     slice array. mega2's obj-finalize loses its 204-candidate loop and LDS
//     staging entirely: 12 coalesced slice loads + 2 gathers + epilogue.
// Dispatches: mega1 (768 blocks; block 0 zeroes accs) -> mega2 (482 blocks;
// last block combines into out[0] via counter in accs[8]).

#define NB 32
#define NH 778
#define NO 3000
#define NZ 64
#define NP 204

#define P_OBJ 4
#define OBJ_PTS 1024
#define OBJ_TILES 3                   // ceil(3000/1024)
#define JSPLIT 4
#define JCH 195                       // ceil(778/4)
#define HC 12                         // hand-side obj chunks
#define HCS 250                       // 3000/12
#define OBJ_BLKS (NB * OBJ_TILES * JSPLIT)    // 384
#define HAND_BLKS (NB * HC)                   // 384
#define T2 12                         // mega2 obj tiles (256 pts)
#define FIN_OBJ_BLKS (NB * T2)                // 384
#define FIN_TAIL_BLKS ((NB * NH + 255) / 256) // 98
#define FIN_BLKS (FIN_OBJ_BLKS + FIN_TAIL_BLKS) // 482

#define NKEY (NB * NO)                // 96000
#define NHT  (NB * NH)                // 24896

typedef unsigned int uint32;

// original order (unused now, kept for PATH C)
__device__ __constant__ int c_prior[NP] = {
  697,698,699,700,712,713,714,715,737,738,739,740,741,743,744,745,746,748,749,750,
  753,754,755,756,757,758,759,760,761,762,763,764,765,766,767,768,
  46,47,48,49,164,165,166,167,194,195,223,237,238,280,281,298,301,317,320,323,
  324,325,326,327,328,329,330,331,332,333,340,341,342,343,344,345,346,347,348,349,
  350,351,352,353,354,355,
  356,357,358,359,375,376,386,387,396,397,402,403,413,429,433,434,435,436,437,438,
  439,440,441,442,443,444,452,453,454,455,456,459,460,461,462,463,464,465,466,467,
  468,469,470,471,484,485,486,496,497,506,507,513,514,524,545,546,547,548,549,550,
  551,552,553,555,563,564,565,566,567,570,572,573,574,575,576,577,578,
  580,581,582,583,600,601,602,614,615,624,625,630,631,641,663,664,665,666,667,668,
  670,672,680,681,682,683,684,686,687,688,689,690,691,692,693,694,695,
  73,96,98,99,772,774,775,777
};

// sorted ascending; per-JCH-split offsets: [0,13) [13,58) [58,131) [131,204)
__device__ __constant__ int c_prior_sorted[NP] = {
  // split 0: j in [0,195)  (13)
  46,47,48,49,73,96,98,99,164,165,166,167,194,
  // split 1: j in [195,390) (45)
  195,223,237,238,280,281,298,301,317,320,323,324,325,326,327,328,329,330,331,
  332,333,340,341,342,343,344,345,346,347,348,349,350,351,352,353,354,355,356,
  357,358,359,375,376,386,387,
  // split 2: j in [390,585) (73)
  396,397,402,403,413,429,433,434,435,436,437,438,439,440,441,442,443,444,452,
  453,454,455,456,459,460,461,462,463,464,465,466,467,468,469,470,471,484,485,
  486,496,497,506,507,513,514,524,545,546,547,548,549,550,551,552,553,555,563,
  564,565,566,567,570,572,573,574,575,576,577,578,580,581,582,583,
  // split 3: j in [585,778) (73)
  600,601,602,614,615,624,625,630,631,641,663,664,665,666,667,668,670,672,680,
  681,682,683,684,686,687,688,689,690,691,692,693,694,695,697,698,699,700,712,
  713,714,715,737,738,739,740,741,743,744,745,746,748,749,750,753,754,755,756,
  757,758,759,760,761,762,763,764,765,766,767,768,772,774,775,777
};
__device__ __constant__ int c_psplit[JSPLIT + 1] = {0, 13, 58, 131, 204};

__device__ inline float wave_sum(float v) {
  v += __shfl_down(v, 32);
  v += __shfl_down(v, 16);
  v += __shfl_down(v, 8);
  v += __shfl_down(v, 4);
  v += __shfl_down(v, 2);
  v += __shfl_down(v, 1);
  return v;
}

// pack candidate index into low 10 mantissa bits; float order ~ (t, j)
__device__ inline float packkey(float t, int j) {
  return __uint_as_float((__float_as_uint(t) & 0xFFFFFC00u) | (uint32)j);
}

// ======================= dispatch 1: mega1 =======================
// accs: 0 penetr, 1 npts, 2 contact, 3 consist, 4 loss_o, 5 loss_h,
//       6 recon_sq, 7 kld, 8 counter(int)
__global__ __launch_bounds__(256) void mega1a(
    const float* __restrict__ recon, const float* __restrict__ gt,
    const float* __restrict__ obj,
    float* __restrict__ keyR, float* __restrict__ keyG,
    float* __restrict__ priorK,
    float* __restrict__ minHR, float* __restrict__ minHG,
    float* __restrict__ accs)
{
  const int bid = blockIdx.x;
  const int tid = threadIdx.x;

  if (bid == 0 && tid < 16) accs[tid] = 0.0f;  // consumed after kernel boundary

  if (bid < OBJ_BLKS) {
    // ---- obj -> hand NN, j-split 4, + in-pass partial prior-NN ----
    __shared__ float4 shA[JCH];   // recon split
    __shared__ float4 shB[JCH];   // gt split
    const int b     = bid / (OBJ_TILES * JSPLIT);
    const int rem   = bid % (OBJ_TILES * JSPLIT);
    const int tile  = rem / JSPLIT;
    const int split = rem % JSPLIT;
    const int jbase = split * JCH;
    const int jcnt  = (NH - jbase < JCH) ? (NH - jbase) : JCH;

    for (int i = tid; i < jcnt; i += 256) {
      const float* p = recon + ((size_t)b * NH + jbase + i) * 3;
      float x = p[0], y = p[1], z = p[2];
      shA[i] = make_float4(x, y, z, x*x + y*y + z*z);
      const float* q = gt + ((size_t)b * NH + jbase + i) * 3;
      float gx = q[0], gy = q[1], gz = q[2];
      shB[i] = make_float4(gx, gy, gz, gx*gx + gy*gy + gz*gz);
    }
    __syncthreads();

    float nx[P_OBJ], ny[P_OBJ], nz[P_OBJ];
    int ob[P_OBJ]; bool val[P_OBJ];
    #pragma unroll
    for (int m = 0; m < P_OBJ; ++m) {
      int o = tile * OBJ_PTS + m * 256 + tid;
      ob[m] = o; val[m] = (o < NO);
      float x = 0.f, y = 0.f, z = 0.f;
      if (val[m]) {
        const float* op = obj + ((size_t)b * NO + o) * 3;
        x = op[0]; y = op[1]; z = op[2];
      }
      nx[m] = -2.f * x; ny[m] = -2.f * y; nz[m] = -2.f * z;
    }

    float bR[P_OBJ], bG[P_OBJ];
    #pragma unroll
    for (int m = 0; m < P_OBJ; ++m) { bR[m] = 3.4e38f; bG[m] = 3.4e38f; }

    int i = 0;
    for (; i + 1 < jcnt; i += 2) {
      float4 h0 = shA[i], h1 = shA[i + 1];
      #pragma unroll
      for (int m = 0; m < P_OBJ; ++m) {
        float t0 = fmaf(nx[m], h0.x, h0.w); t0 = fmaf(ny[m], h0.y, t0); t0 = fmaf(nz[m], h0.z, t0);
        float t1 = fmaf(nx[m], h1.x, h1.w); t1 = fmaf(ny[m], h1.y, t1); t1 = fmaf(nz[m], h1.z, t1);
        bR[m] = fminf(bR[m], fminf(packkey(t0, jbase + i), packkey(t1, jbase + i + 1)));
      }
      float4 g0 = shB[i], g1 = shB[i + 1];
      #pragma unroll
      for (int m = 0; m < P_OBJ; ++m) {
        float t0 = fmaf(nx[m], g0.x, g0.w); t0 = fmaf(ny[m], g0.y, t0); t0 = fmaf(nz[m], g0.z, t0);
        float t1 = fmaf(nx[m], g1.x, g1.w); t1 = fmaf(ny[m], g1.y, t1); t1 = fmaf(nz[m], g1.z, t1);
        bG[m] = fminf(bG[m], fminf(packkey(t0, jbase + i), packkey(t1, jbase + i + 1)));
      }
    }
    if (i < jcnt) {
      float4 h0 = shA[i];
      float4 g0 = shB[i];
      #pragma unroll
      for (int m = 0; m < P_OBJ; ++m) {
        float t0 = fmaf(nx[m], h0.x, h0.w); t0 = fmaf(ny[m], h0.y, t0); t0 = fmaf(nz[m], h0.z, t0);
        bR[m] = fminf(bR[m], packkey(t0, jbase + i));
        float u0 = fmaf(nx[m], g0.x, g0.w); u0 = fmaf(ny[m], g0.y, u0); u0 = fmaf(nz[m], g0.z, u0);
        bG[m] = fminf(bG[m], packkey(u0, jbase + i));
      }
    }

    // partial prior-NN over this split's prior members (recon candidates in shA)
    float bP[P_OBJ];
    #pragma unroll
    for (int m = 0; m < P_OBJ; ++m) bP[m] = 3.4e38f;
    const int pk0 = c_psplit[split], pk1 = c_psplit[split + 1];
    for (int k = pk0; k < pk1; ++k) {
      float4 h = shA[c_prior_sorted[k] - jbase];
      #pragma unroll
      for (int m = 0; m < P_OBJ; ++m) {
        float t = fmaf(nx[m], h.x, h.w);
        t = fmaf(ny[m], h.y, t);
        t = fmaf(nz[m], h.z, t);
        bP[m] = fminf(bP[m], t);
      }
    }

    #pragma unroll
    for (int m = 0; m < P_OBJ; ++m) {
      if (!val[m]) continue;
      const size_t idx = (size_t)split * NKEY + (size_t)b * NO + ob[m];
      keyR[idx] = bR[m];
      keyG[idx] = bG[m];
      priorK[idx] = bP[m];
    }
  } else {
    // ---- hand -> obj NN, 12 chunks, per-chunk t-min slices ----
    __shared__ float4 sO[HCS];
    const int bid2 = bid - OBJ_BLKS;
    const int oc = bid2 % HC;
    const int b  = bid2 / HC;

    const float* Ob = obj + ((size_t)b * NO + oc * HCS) * 3;
    for (int i2 = tid; i2 < HCS; i2 += 256) {
      float x = Ob[3*i2], y = Ob[3*i2+1], z = Ob[3*i2+2];
      sO[i2] = make_float4(x, y, z, x*x + y*y + z*z);
    }
    __syncthreads();

    float nrx[4], nry[4], nrz[4];
    float ngx[4], ngy[4], ngz[4];
    bool val[4];
    #pragma unroll
    for (int m = 0; m < 4; ++m) {
      int j = m * 256 + tid;
      val[m] = (j < NH);
      float rx = 0.f, ry = 0.f, rz = 0.f, gx = 0.f, gy = 0.f, gz = 0.f;
      if (val[m]) {
        const float* rp = recon + ((size_t)b * NH + j) * 3;
        const float* gp = gt    + ((size_t)b * NH + j) * 3;
        rx = rp[0]; ry = rp[1]; rz = rp[2];
        gx = gp[0]; gy = gp[1]; gz = gp[2];
      }
      nrx[m] = -2.f*rx; nry[m] = -2.f*ry; nrz[m] = -2.f*rz;
      ngx[m] = -2.f*gx; ngy[m] = -2.f*gy; ngz[m] = -2.f*gz;
    }

    float mR[4], mG[4];
    #pragma unroll
    for (int m = 0; m < 4; ++m) { mR[m] = 3.4e38f; mG[m] = 3.4e38f; }

    for (int k = 0; k < HCS; k += 2) {
      float4 o0 = sO[k], o1 = sO[k + 1];
      #pragma unroll
      for (int m = 0; m < 4; ++m) {
        float t0 = fmaf(nrx[m], o0.x, o0.w); t0 = fmaf(nry[m], o0.y, t0); t0 = fmaf(nrz[m], o0.z, t0);
        float t1 = fmaf(nrx[m], o1.x, o1.w); t1 = fmaf(nry[m], o1.y, t1); t1 = fmaf(nrz[m], o1.z, t1);
        mR[m] = fminf(mR[m], fminf(t0, t1));
        float u0 = fmaf(ngx[m], o0.x, o0.w); u0 = fmaf(ngy[m], o0.y, u0); u0 = fmaf(ngz[m], o0.z, u0);
        float u1 = fmaf(ngx[m], o1.x, o1.w); u1 = fmaf(ngy[m], o1.y, u1); u1 = fmaf(ngz[m], o1.z, u1);
        mG[m] = fminf(mG[m], fminf(u0, u1));
      }
    }

    #pragma unroll
    for (int m = 0; m < 4; ++m) {
      if (!val[m]) continue;
      int j = m * 256 + tid;
      const size_t idx = (size_t)oc * NHT + (size_t)b * NH + j;
      minHR[idx] = mR[m];
      minHG[idx] = mG[m];
    }
  }
}

// ======================= dispatch 2: mega2 =======================
__global__ __launch_bounds__(256) void mega2a(
    const float* __restrict__ recon, const float* __restrict__ gt,
    const float* __restrict__ rnorm, const float* __restrict__ gnorm,
    const float* __restrict__ obj,
    const float* __restrict__ mean, const float* __restrict__ logv,
    const float* __restrict__ vw,
    const float* __restrict__ keyR, const float* __restrict__ keyG,
    const float* __restrict__ priorK,
    const float* __restrict__ minHR, const float* __restrict__ minHG,
    float* __restrict__ accs, float* __restrict__ out)
{
  __shared__ float red[4][5];
  const int bid = blockIdx.x;
  const int tid = threadIdx.x;
  const int lane = tid & 63, wv = tid >> 6;

  if (bid < FIN_OBJ_BLKS) {
    // ---- obj finalize: 12 slice loads + 2 gathers + epilogue (no staging) ----
    const int b = bid / T2;
    const int tile = bid % T2;
    const int o = tile * 256 + tid;
    float penetr = 0.f, nptsv = 0.f, contactv = 0.f, consistv = 0.f, lossov = 0.f;
    if (o < NO) {
      const float* op = obj + ((size_t)b * NO + o) * 3;
      const float ox = op[0], oy = op[1], oz = op[2];
      const float o2 = ox*ox + oy*oy + oz*oz;
      const size_t base = (size_t)b * NO + o;

      float kR = 3.4e38f, kG = 3.4e38f, bP = 3.4e38f;
      #pragma unroll
      for (int s = 0; s < JSPLIT; ++s) {
        kR = fminf(kR, keyR[(size_t)s * NKEY + base]);
        kG = fminf(kG, keyG[(size_t)s * NKEY + base]);
        bP = fminf(bP, priorK[(size_t)s * NKEY + base]);
      }
      uint32 kRb = __float_as_uint(kR), kGb = __float_as_uint(kG);
      int idxR = (int)(kRb & 0x3FFu), idxG = (int)(kGb & 0x3FFu);
      float d2R = fmaxf(__uint_as_float(kRb & 0xFFFFFC00u) + o2, 0.f);
      float d2G = fmaxf(__uint_as_float(kGb & 0xFFFFFC00u) + o2, 0.f);
      float d2P = fmaxf(bP + o2, 0.f);

      const float* hR = recon + ((size_t)b * NH + idxR) * 3;
      const float* nR = rnorm + ((size_t)b * NH + idxR) * 3;
      float dotR = (ox - hR[0]) * nR[0] + (oy - hR[1]) * nR[1] + (oz - hR[2]) * nR[2];
      const float* hG = gt + ((size_t)b * NH + idxG) * 3;
      const float* nG = gnorm + ((size_t)b * NH + idxG) * 3;
      float dotG = (ox - hG[0]) * nG[0] + (oy - hG[1]) * nG[1] + (oz - hG[2]) * nG[2];

      float sgnR = (dotR > 0.f) ? 1.f : ((dotR < 0.f) ? -1.f : 0.f);
      float sgnG = (dotG > 0.f) ? 1.f : ((dotG < 0.f) ? -1.f : 0.f);
      float sR_ = sqrtf(d2R), sG_ = sqrtf(d2G);
      float o2h = sR_ * sgnR, o2hg = sG_ * sgnG;

      bool interior = dotR < 0.f;
      bool cmap = sG_ < 0.005f;
      bool rcmap = sR_ < 0.005f;

      penetr   = interior ? d2R : 0.f;
      nptsv    = cmap ? 1.f : 0.f;
      contactv = cmap ? d2P : 0.f;
      consistv = (cmap && rcmap) ? 1.f : 0.f;
      float w = (o2h < 0.f) ? 1.5f
              : (((o2hg < 0.01f) && (o2hg > -0.005f)) ? 1.f : 0.1f);
      lossov = fabsf(o2h - o2hg) * w;
    }

    float vals[5] = {penetr, nptsv, contactv, consistv, lossov};
    #pragma unroll
    for (int q = 0; q < 5; ++q) {
      float s = wave_sum(vals[q]);
      if (lane == 0) red[wv][q] = s;
    }
    __syncthreads();
    if (tid < 5) {
      float s = red[0][tid] + red[1][tid] + red[2][tid] + red[3][tid];
      atomicAdd(&accs[tid], s);
    }
  } else {
    // ---- tail: reduce hand-chunk mins, loss_h, recon_loss, KLD ----
    const int t = (bid - FIN_OBJ_BLKS) * 256 + tid;
    float lossh = 0.f, rsum = 0.f, ksum = 0.f;
    if (t < NB * NH) {
      const float* rp = recon + (size_t)t * 3;
      const float* gp = gt + (size_t)t * 3;
      float rx = rp[0], ry = rp[1], rz = rp[2];
      float gx = gp[0], gy = gp[1], gz = gp[2];
      float d0 = rx - gx, d1 = ry - gy, d2 = rz - gz;
      rsum = d0*d0 + d1*d1 + d2*d2;

      float tR[HC], tG[HC];
      #pragma unroll
      for (int c = 0; c < HC; ++c) {
        tR[c] = minHR[(size_t)c * NHT + t];
        tG[c] = minHG[(size_t)c * NHT + t];
      }
      float mRt = tR[0], mGt = tG[0];
      #pragma unroll
      for (int c = 1; c < HC; ++c) {
        mRt = fminf(mRt, tR[c]);
        mGt = fminf(mGt, tG[c]);
      }
      float r2 = rx*rx + ry*ry + rz*rz;
      float g2 = gx*gx + gy*gy + gz*gz;
      float d2Rh = fmaxf(mRt + r2, 0.f);
      float d2Gh = fmaxf(mGt + g2, 0.f);
      int j = t % NH;
      lossh = fabsf(sqrtf(d2Rh) - sqrtf(d2Gh)) * powf(vw[j], 0.4f);
    }
    if (t < NB * NZ) {
      float m = mean[t], lv = logv[t];
      ksum = 1.f + lv - m * m - expf(lv);
    }
    float vals[3] = {lossh, rsum, ksum};
    #pragma unroll
    for (int q = 0; q < 3; ++q) {
      float s = wave_sum(vals[q]);
      if (lane == 0) red[wv][q] = s;
    }
    __syncthreads();
    if (tid < 3) {
      float s = red[0][tid] + red[1][tid] + red[2][tid] + red[3][tid];
      atomicAdd(&accs[5 + tid], s);
    }
  }

  // ---- fused final: last block combines ----
  __syncthreads();
  if (tid == 0) {
    __threadfence();
    int* cnt = (int*)(accs + 8);
    int old = atomicAdd(cnt, 1);
    if (old == FIN_BLKS - 1) {
      float a[8];
      #pragma unroll
      for (int q = 0; q < 8; ++q) a[q] = atomicAdd(&accs[q], 0.0f);
      const float recon_loss = a[6] / (float)NB;
      const float kld = -0.5f * a[7] / (float)NB * 10.f;
      const float penetr = 100.f * a[0] / (float)NB;
      const float npts = a[1];
      const float contact = (npts > 0.f) ? (3000.f * a[2] / ((float)NB * npts)) : 0.f;
      const float consistency = -5.f * a[3] / (npts + 0.0001f);
      const float lossh = 35.f * (1.f - 0.005f) * (a[5] / (float)(NB * NH));
      const float losso = 30.f * (1.f - 0.005f) * (a[4] / (float)(NB * NO));
      out[0] = recon_loss + 0.1f * kld + 1000.f * penetr + 10.f * contact
             + 10.f * consistency + lossh + losso;
    }
  }
}

// =========================== PATH C (tiny ws fallback) ===========================
__global__ __launch_bounds__(256) void obj_mono(
    const float* __restrict__ recon, const float* __restrict__ gt,
    const float* __restrict__ rnorm, const float* __restrict__ gnorm,
    const float* __restrict__ obj, float* __restrict__ accs)
{
  __shared__ float4 sR[NH];
  __shared__ float4 sG[NH];
  __shared__ float red[4][5];
  const int b = blockIdx.x / 12;
  const int tile = blockIdx.x % 12;
  const int tid = threadIdx.x;
  for (int i = tid; i < NH; i += 256) {
    const float* p = recon + ((size_t)b * NH + i) * 3;
    float x = p[0], y = p[1], z = p[2];
    sR[i] = make_float4(x, y, z, x*x + y*y + z*z);
    const float* q = gt + ((size_t)b * NH + i) * 3;
    float gx = q[0], gy = q[1], gz = q[2];
    sG[i] = make_float4(gx, gy, gz, gx*gx + gy*gy + gz*gz);
  }
  __syncthreads();
  const int o = tile * 256 + tid;
  float penetr = 0.f, nptsv = 0.f, contactv = 0.f, consistv = 0.f, lossov = 0.f;
  if (o < NO) {
    const float* op = obj + ((size_t)b * NO + o) * 3;
    const float ox = op[0], oy = op[1], oz = op[2];
    const float nx = -2.f*ox, ny = -2.f*oy, nz = -2.f*oz;
    const float o2 = ox*ox + oy*oy + oz*oz;
    float bR = 3.4e38f, bG = 3.4e38f; int iR = 0, iG = 0;
    for (int i = 0; i < NH; ++i) {
      float4 h = sR[i];
      float t = fmaf(nx, h.x, h.w); t = fmaf(ny, h.y, t); t = fmaf(nz, h.z, t);
      if (t < bR) { bR = t; iR = i; }
      float4 g = sG[i];
      float u = fmaf(nx, g.x, g.w); u = fmaf(ny, g.y, u); u = fmaf(nz, g.z, u);
      if (u < bG) { bG = u; iG = i; }
    }
    float bP = 3.4e38f;
    for (int k = 0; k < NP; ++k) {
      float4 h = sR[c_prior[k]];
      float t = fmaf(nx, h.x, h.w); t = fmaf(ny, h.y, t); t = fmaf(nz, h.z, t);
      bP = fminf(bP, t);
    }
    float d2R = fmaxf(bR + o2, 0.f);
    float d2G = fmaxf(bG + o2, 0.f);
    float d2P = fmaxf(bP + o2, 0.f);
    float4 hR = sR[iR];
    const float* nR = rnorm + ((size_t)b * NH + iR) * 3;
    float dotR = (ox-hR.x)*nR[0] + (oy-hR.y)*nR[1] + (oz-hR.z)*nR[2];
    float4 hG = sG[iG];
    const float* nG = gnorm + ((size_t)b * NH + iG) * 3;
    float dotG = (ox-hG.x)*nG[0] + (oy-hG.y)*nG[1] + (oz-hG.z)*nG[2];
    float sgnR = (dotR > 0.f) ? 1.f : ((dotR < 0.f) ? -1.f : 0.f);
    float sgnG = (dotG > 0.f) ? 1.f : ((dotG < 0.f) ? -1.f : 0.f);
    float sR_ = sqrtf(d2R), sG_ = sqrtf(d2G);
    float o2h = sR_*sgnR, o2hg = sG_*sgnG;
    bool interior = dotR < 0.f;
    bool cmap = sG_ < 0.005f, rcmap = sR_ < 0.005f;
    penetr = interior ? d2R : 0.f;
    nptsv = cmap ? 1.f : 0.f;
    contactv = cmap ? d2P : 0.f;
    consistv = (cmap && rcmap) ? 1.f : 0.f;
    float w = (o2h < 0.f) ? 1.5f : (((o2hg < 0.01f) && (o2hg > -0.005f)) ? 1.f : 0.1f);
    lossov = fabsf(o2h - o2hg) * w;
  }
  float vals[5] = {penetr, nptsv, contactv, consistv, lossov};
  const int lane = tid & 63, wv = tid >> 6;
  for (int q = 0; q < 5; ++q) {
    float s = wave_sum(vals[q]);
    if (lane == 0) red[wv][q] = s;
  }
  __syncthreads();
  if (tid < 5) {
    float s = red[0][tid] + red[1][tid] + red[2][tid] + red[3][tid];
    atomicAdd(&accs[tid], s);
  }
}

__global__ __launch_bounds__(256) void hand_full(
    const float* __restrict__ recon, const float* __restrict__ gt,
    const float* __restrict__ obj, const float* __restrict__ vw,
    float* __restrict__ accs)
{
  __shared__ float4 sO[500];
  __shared__ float red[4];
  const int b = blockIdx.x >> 2;
  const int j = ((blockIdx.x & 3) << 8) + threadIdx.x;
  const bool valid = j < NH;
  float rx=0,ry=0,rz=0,gx=0,gy=0,gz=0;
  if (valid) {
    const float* rp = recon + ((size_t)b * NH + j) * 3;
    const float* gp = gt + ((size_t)b * NH + j) * 3;
    rx=rp[0];ry=rp[1];rz=rp[2]; gx=gp[0];gy=gp[1];gz=gp[2];
  }
  const float nrx=-2.f*rx, nry=-2.f*ry, nrz=-2.f*rz;
  const float ngx=-2.f*gx, ngy=-2.f*gy, ngz=-2.f*gz;
  const float r2 = rx*rx+ry*ry+rz*rz, g2 = gx*gx+gy*gy+gz*gz;
  float mR = 3.4e38f, mG = 3.4e38f;
  for (int oc = 0; oc < 6; ++oc) {
    __syncthreads();
    const float* Ob = obj + ((size_t)b * NO + oc * 500) * 3;
    for (int i = threadIdx.x; i < 500; i += 256) {
      float x = Ob[3*i], y = Ob[3*i+1], z = Ob[3*i+2];
      sO[i] = make_float4(x, y, z, x*x + y*y + z*z);
    }
    __syncthreads();
    if (valid) {
      for (int k = 0; k < 500; ++k) {
        float4 o4 = sO[k];
        float t = fmaf(nrx,o4.x,o4.w); t = fmaf(nry,o4.y,t); t = fmaf(nrz,o4.z,t);
        mR = fminf(mR, t);
        float u = fmaf(ngx,o4.x,o4.w); u = fmaf(ngy,o4.y,u); u = fmaf(ngz,o4.z,u);
        mG = fminf(mG, u);
      }
    }
  }
  float lossh = valid ? fabsf(sqrtf(fmaxf(mR+r2,0.f)) - sqrtf(fmaxf(mG+g2,0.f))) * powf(vw[j], 0.4f) : 0.f;
  const int lane = threadIdx.x & 63, wv = threadIdx.x >> 6;
  float s = wave_sum(lossh);
  if (lane == 0) red[wv] = s;
  __syncthreads();
  if (threadIdx.x == 0) atomicAdd(&accs[5], red[0]+red[1]+red[2]+red[3]);
}

__global__ __launch_bounds__(256) void tail_nomins(
    const float* __restrict__ recon, const float* __restrict__ gt,
    const float* __restrict__ mean, const float* __restrict__ logv,
    float* __restrict__ accs)
{
  __shared__ float red[4][2];
  const int t = blockIdx.x * 256 + threadIdx.x;
  float rsum = 0.f, ksum = 0.f;
  if (t < NB * NH) {
    const float* rp = recon + (size_t)t * 3;
    const float* gp = gt + (size_t)t * 3;
    float d0 = rp[0]-gp[0], d1 = rp[1]-gp[1], d2 = rp[2]-gp[2];
    rsum = d0*d0 + d1*d1 + d2*d2;
  }
  if (t < NB * NZ) {
    float m = mean[t], lv = logv[t];
    ksum = 1.f + lv - m*m - expf(lv);
  }
  float vals[2] = {rsum, ksum};
  const int lane = threadIdx.x & 63, wv = threadIdx.x >> 6;
  for (int q = 0; q < 2; ++q) {
    float s = wave_sum(vals[q]);
    if (lane == 0) red[wv][q] = s;
  }
  __syncthreads();
  if (threadIdx.x < 2) {
    float s = red[0][threadIdx.x] + red[1][threadIdx.x] + red[2][threadIdx.x] + red[3][threadIdx.x];
    atomicAdd(&accs[6 + threadIdx.x], s);
  }
}

__global__ void init_small(float* accs) {
  int t = threadIdx.x;
  if (t < 8) accs[t] = 0.0f;
}

__global__ void final_fb(const float* __restrict__ a, float* __restrict__ out) {
  const float recon_loss = a[6] / (float)NB;
  const float kld = -0.5f * a[7] / (float)NB * 10.f;
  const float penetr = 100.f * a[0] / (float)NB;
  const float npts = a[1];
  const float contact = (npts > 0.f) ? (3000.f * a[2] / ((float)NB * npts)) : 0.f;
  const float consistency = -5.f * a[3] / (npts + 0.0001f);
  const float lossh = 35.f * (1.f - 0.005f) * (a[5] / (float)(NB * NH));
  const float losso = 30.f * (1.f - 0.005f) * (a[4] / (float)(NB * NO));
  out[0] = recon_loss + 0.1f*kld + 1000.f*penetr + 10.f*contact + 10.f*consistency + lossh + losso;
}

extern "C" void kernel_launch(void* const* d_in, const int* in_sizes, int n_in,
                              void* d_out, int out_size, void* d_ws, size_t ws_size,
                              hipStream_t stream) {
  const float* recon = (const float*)d_in[0];
  const float* gt    = (const float*)d_in[1];
  const float* rnorm = (const float*)d_in[2];
  const float* gnorm = (const float*)d_in[3];
  const float* obj   = (const float*)d_in[4];
  const float* mean  = (const float*)d_in[5];
  const float* logv  = (const float*)d_in[6];
  const float* vw    = (const float*)d_in[7];
  float* out = (float*)d_out;

  // ws: accs[16] @0 | slices @256: keyR[4N] keyG[4N] priorK[4N] minHR[12H] minHG[12H]
  float* accs   = (float*)d_ws;
  float* keyR   = (float*)((char*)d_ws + 256);
  float* keyG   = keyR + (size_t)JSPLIT * NKEY;
  float* priorK = keyG + (size_t)JSPLIT * NKEY;
  float* minHR  = priorK + (size_t)JSPLIT * NKEY;
  float* minHG  = minHR + (size_t)HC * NHT;
  const size_t neededA = 256 + (3ull * JSPLIT * NKEY + 2ull * HC * NHT) * sizeof(float);

  if (ws_size >= neededA) {
    mega1a<<<OBJ_BLKS + HAND_BLKS, 256, 0, stream>>>(
        recon, gt, obj, keyR, keyG, priorK, minHR, minHG, accs);
    mega2a<<<FIN_BLKS, 256, 0, stream>>>(
        recon, gt, rnorm, gnorm, obj, mean, logv, vw,
        keyR, keyG, priorK, minHR, minHG, accs, out);
  } else {
    init_small<<<1, 64, 0, stream>>>(accs);
    obj_mono<<<NB * 12, 256, 0, stream>>>(recon, gt, rnorm, gnorm, obj, accs);
    hand_full<<<NB * 4, 256, 0, stream>>>(recon, gt, obj, vw, accs);
    tail_nomins<<<(NB * NH + 255) / 256, 256, 0, stream>>>(recon, gt, mean, logv, accs);
    final_fb<<<1, 1, 0, stream>>>(accs, out);
  }
}